// Round 4
// baseline (155.288 us; speedup 1.0000x reference)
//
#include <hip/hip_runtime.h>
#include <stdint.h>

#define B_ROWS 1048576

typedef __fp16 h2 __attribute__((ext_vector_type(2)));

// ws float layout:
//  [0..15]    bn sums (sum[8], sumsq[8]) -- memset + bn_stats atomicAdd
//  [16..385]  packed f16x2 weights (as uint32), 370 dwords
//  [386..450] f32 biases, 65 floats
#define WPK_OFF 16
#define BIA_OFF 386
// packed-weight dword offsets per layer
#define W_FM 0
#define W_C1 64
#define W_P1 192
#define W_C2 288
#define W_P2 336
#define W_C3 352
#define W_R  360
#define W_H  368
// bias float offsets per layer
#define B_FM 0
#define B_C1 16
#define B_P1 32
#define B_C2 44
#define B_P2 52
#define B_C3 56
#define B_R  60
#define B_H  64

__device__ __forceinline__ float fast_tanh(float x) {
    float e = __builtin_amdgcn_exp2f(x * 2.8853900817779268f);
    return 1.0f - 2.0f * __builtin_amdgcn_rcpf(e + 1.0f);
}

__device__ __forceinline__ float fast_sigmoid(float x) {
    float e = __builtin_amdgcn_exp2f(x * -1.4426950408889634f);
    return __builtin_amdgcn_rcpf(1.0f + e);
}

// ---------------- pass 1: per-feature sum / sumsq over all rows ----------------
__global__ __launch_bounds__(256) void bn_stats(const float* __restrict__ x,
                                                float* __restrict__ ws) {
    const int tid = blockIdx.x * 256 + threadIdx.x;   // 0..262143 (1024 blocks)
    float s[8], q[8];
#pragma unroll
    for (int c = 0; c < 8; ++c) { s[c] = 0.f; q[c] = 0.f; }
    const float4* x4 = (const float4*)x;
#pragma unroll
    for (int k = 0; k < 4; ++k) {
        int r = tid + k * 262144;
        float4 a = x4[2 * r];
        float4 b = x4[2 * r + 1];
        s[0] += a.x; s[1] += a.y; s[2] += a.z; s[3] += a.w;
        s[4] += b.x; s[5] += b.y; s[6] += b.z; s[7] += b.w;
        q[0] += a.x * a.x; q[1] += a.y * a.y; q[2] += a.z * a.z; q[3] += a.w * a.w;
        q[4] += b.x * b.x; q[5] += b.y * b.y; q[6] += b.z * b.z; q[7] += b.w * b.w;
    }
#pragma unroll
    for (int off = 32; off > 0; off >>= 1) {
#pragma unroll
        for (int c = 0; c < 8; ++c) {
            s[c] += __shfl_down(s[c], off);
            q[c] += __shfl_down(q[c], off);
        }
    }
    __shared__ float red[4][16];
    const int lane = threadIdx.x & 63;
    const int wave = threadIdx.x >> 6;
    if (lane == 0) {
#pragma unroll
        for (int c = 0; c < 8; ++c) { red[wave][c] = s[c]; red[wave][8 + c] = q[c]; }
    }
    __syncthreads();
    if (threadIdx.x < 16) {
        float acc = red[0][threadIdx.x] + red[1][threadIdx.x] +
                    red[2][threadIdx.x] + red[3][threadIdx.x];
        atomicAdd(&ws[threadIdx.x], acc);
    }
}

// ---------------- pass 1.5: fold BN into L1, pack all weights to f16x2 ---------
template<int DIN, int DOUT>
__device__ void pack_layer(const float* __restrict__ w, const float* __restrict__ b,
                           uint32_t* __restrict__ wdst, float* __restrict__ bdst,
                           const float* sc, const float* sh, bool fold) {
    for (int idx = threadIdx.x; idx < DOUT * (DIN / 2); idx += blockDim.x) {
        int j = idx / (DIN / 2), i2 = idx % (DIN / 2);
        float w0 = w[(2 * i2) * DOUT + j];
        float w1 = w[(2 * i2 + 1) * DOUT + j];
        if (fold) { w0 *= sc[2 * i2]; w1 *= sc[2 * i2 + 1]; }
        h2 h; h.x = (__fp16)w0; h.y = (__fp16)w1;   // RTE converts
        wdst[j * (DIN / 2) + i2] = __builtin_bit_cast(uint32_t, h);
    }
    for (int j = threadIdx.x; j < DOUT; j += blockDim.x) {
        float bb = b[j];
        if (fold) {
#pragma unroll
            for (int i = 0; i < 8; ++i) bb += sh[i] * w[i * DOUT + j];
        }
        bdst[j] = bb;
    }
}

__global__ __launch_bounds__(256) void prep(
    float* __restrict__ ws,
    const float* __restrict__ bn_g, const float* __restrict__ bn_b,
    const float* __restrict__ w_fm, const float* __restrict__ b_fm,
    const float* __restrict__ w_c1, const float* __restrict__ b_c1,
    const float* __restrict__ w_p1, const float* __restrict__ b_p1,
    const float* __restrict__ w_c2, const float* __restrict__ b_c2,
    const float* __restrict__ w_p2, const float* __restrict__ b_p2,
    const float* __restrict__ w_c3, const float* __restrict__ b_c3,
    const float* __restrict__ w_r,  const float* __restrict__ b_r,
    const float* __restrict__ w_h,  const float* __restrict__ b_h)
{
    const float invB = 1.0f / (float)B_ROWS;
    float sc[8], sh[8];
#pragma unroll
    for (int c = 0; c < 8; ++c) {
        float mu  = ws[c] * invB;
        float var = fmaf(-mu, mu, ws[8 + c] * invB);
        float s   = bn_g[c] * rsqrtf(var + 1e-5f);
        sc[c] = s;
        sh[c] = fmaf(-mu, s, bn_b[c]);
    }
    uint32_t* wpk = (uint32_t*)(ws + WPK_OFF);
    float*    bpk = ws + BIA_OFF;
    pack_layer<8, 16>(w_fm, b_fm, wpk + W_FM, bpk + B_FM, sc, sh, true);
    pack_layer<16,16>(w_c1, b_c1, wpk + W_C1, bpk + B_C1, sc, sh, false);
    pack_layer<16,12>(w_p1, b_p1, wpk + W_P1, bpk + B_P1, sc, sh, false);
    pack_layer<12, 8>(w_c2, b_c2, wpk + W_C2, bpk + B_C2, sc, sh, false);
    pack_layer<8,  4>(w_p2, b_p2, wpk + W_P2, bpk + B_P2, sc, sh, false);
    pack_layer<4,  4>(w_c3, b_c3, wpk + W_C3, bpk + B_C3, sc, sh, false);
    pack_layer<4,  4>(w_r,  b_r,  wpk + W_R,  bpk + B_R,  sc, sh, false);
    pack_layer<4,  1>(w_h,  b_h,  wpk + W_H,  bpk + B_H,  sc, sh, false);
}

// ---------------- dot2-based layer: f16 inputs, f32 accumulate -----------------
template<int DIN, int DOUT>
__device__ __forceinline__ void layer_dot(const h2* __restrict__ apk, float* __restrict__ out,
                                          const uint32_t* __restrict__ wpk,
                                          const float* __restrict__ bias) {
#pragma unroll
    for (int j = 0; j < DOUT; ++j) {
        float acc = bias[j];
#pragma unroll
        for (int i2 = 0; i2 < DIN / 2; ++i2) {
            h2 w = __builtin_bit_cast(h2, wpk[j * (DIN / 2) + i2]);
            acc = __builtin_amdgcn_fdot2(apk[i2], w, acc, false);
        }
        out[j] = acc;
    }
}

template<int N>   // N even: tanh then pack to f16 pairs
__device__ __forceinline__ void tanh_pack(const float* __restrict__ in, h2* __restrict__ apk) {
#pragma unroll
    for (int k = 0; k < N / 2; ++k) {
        float t0 = fast_tanh(in[2 * k]);
        float t1 = fast_tanh(in[2 * k + 1]);
        apk[k] = __builtin_amdgcn_cvt_pkrtz(t0, t1);
    }
}

// ---------------- pass 2: MLP chain, 1 row/thread ------------------------------
__global__ __launch_bounds__(256) void qcnn_main(
    const float* __restrict__ x,
    const float* __restrict__ ws, float* __restrict__ out)
{
    const uint32_t* wpk = (const uint32_t*)(ws + WPK_OFF);
    const float*    bpk = ws + BIA_OFF;

    const int tid = blockIdx.x * 256 + threadIdx.x;   // 0..1048575
    const float4* x4 = (const float4*)x;
    float4 xa = x4[2 * tid], xb = x4[2 * tid + 1];

    // BN is folded into L1 weights -> pack raw x
    h2 a8[4];
    a8[0] = __builtin_amdgcn_cvt_pkrtz(xa.x, xa.y);
    a8[1] = __builtin_amdgcn_cvt_pkrtz(xa.z, xa.w);
    a8[2] = __builtin_amdgcn_cvt_pkrtz(xb.x, xb.y);
    a8[3] = __builtin_amdgcn_cvt_pkrtz(xb.z, xb.w);

    float o16[16]; h2 p16[8];
    layer_dot<8, 16>(a8, o16, wpk + W_FM, bpk + B_FM);  tanh_pack<16>(o16, p16);
    float o16b[16]; h2 p16b[8];
    layer_dot<16,16>(p16, o16b, wpk + W_C1, bpk + B_C1); tanh_pack<16>(o16b, p16b);
    float o12[12]; h2 p12[6];
    layer_dot<16,12>(p16b, o12, wpk + W_P1, bpk + B_P1); tanh_pack<12>(o12, p12);
    float o8[8]; h2 p8[4];
    layer_dot<12, 8>(p12, o8, wpk + W_C2, bpk + B_C2);   tanh_pack<8>(o8, p8);
    float o4[4]; h2 p4[2];
    layer_dot<8,  4>(p8, o4, wpk + W_P2, bpk + B_P2);    tanh_pack<4>(o4, p4);
    float c4[4];
    layer_dot<4,  4>(p4, c4, wpk + W_C3, bpk + B_C3);
#pragma unroll
    for (int j = 0; j < 4; ++j) c4[j] = fast_tanh(c4[j]);
    h2 pc4[2];
    pc4[0] = __builtin_amdgcn_cvt_pkrtz(c4[0], c4[1]);
    pc4[1] = __builtin_amdgcn_cvt_pkrtz(c4[2], c4[3]);
    float r4[4];
    layer_dot<4,  4>(pc4, r4, wpk + W_R, bpk + B_R);
#pragma unroll
    for (int j = 0; j < 4; ++j) c4[j] += fmaxf(r4[j], 0.f);
    h2 ph[2];
    ph[0] = __builtin_amdgcn_cvt_pkrtz(c4[0], c4[1]);
    ph[1] = __builtin_amdgcn_cvt_pkrtz(c4[2], c4[3]);
    float oh[1];
    layer_dot<4,  1>(ph, oh, wpk + W_H, bpk + B_H);
    out[tid] = fast_sigmoid(oh[0]);
}

extern "C" void kernel_launch(void* const* d_in, const int* in_sizes, int n_in,
                              void* d_out, int out_size, void* d_ws, size_t ws_size,
                              hipStream_t stream) {
    const float* x    = (const float*)d_in[0];
    const float* bn_g = (const float*)d_in[1];
    const float* bn_b = (const float*)d_in[2];
    const float* w_fm = (const float*)d_in[3];
    const float* b_fm = (const float*)d_in[4];
    const float* w_c1 = (const float*)d_in[5];
    const float* b_c1 = (const float*)d_in[6];
    const float* w_p1 = (const float*)d_in[7];
    const float* b_p1 = (const float*)d_in[8];
    const float* w_c2 = (const float*)d_in[9];
    const float* b_c2 = (const float*)d_in[10];
    const float* w_p2 = (const float*)d_in[11];
    const float* b_p2 = (const float*)d_in[12];
    const float* w_c3 = (const float*)d_in[13];
    const float* b_c3 = (const float*)d_in[14];
    const float* w_r  = (const float*)d_in[15];
    const float* b_r  = (const float*)d_in[16];
    const float* w_h  = (const float*)d_in[17];
    const float* b_h  = (const float*)d_in[18];
    float* out = (float*)d_out;
    float* ws  = (float*)d_ws;

    (void)hipMemsetAsync(d_ws, 0, 16 * sizeof(float), stream);
    bn_stats<<<1024, 256, 0, stream>>>(x, ws);
    prep<<<1, 256, 0, stream>>>(ws, bn_g, bn_b, w_fm, b_fm, w_c1, b_c1, w_p1, b_p1,
                                w_c2, b_c2, w_p2, b_p2, w_c3, b_c3, w_r, b_r, w_h, b_h);
    qcnn_main<<<B_ROWS / 256, 256, 0, stream>>>(x, ws, out);
}

// Round 5
// 153.349 us; speedup vs baseline: 1.0126x; 1.0126x over previous
//
#include <hip/hip_runtime.h>
#include <stdint.h>

#define B_ROWS 1048576
#define ROWS_PER_THREAD 2
#define MAIN_BLOCKS (B_ROWS / (256 * ROWS_PER_THREAD))   // 2048

typedef __fp16 h2 __attribute__((ext_vector_type(2)));

// ws float layout:
//  [0..15]    bn sums (sum[8], sumsq[8]) -- memset + bn_stats atomicAdd
//  [16..385]  packed f16x2 weights (as uint32), 370 dwords
//  [386..450] f32 biases, 65 floats
#define WPK_OFF 16
#define BIA_OFF 386
#define W_FM 0
#define W_C1 64
#define W_P1 192
#define W_C2 288
#define W_P2 336
#define W_C3 352
#define W_R  360
#define W_H  368
#define B_FM 0
#define B_C1 16
#define B_P1 32
#define B_C2 44
#define B_P2 52
#define B_C3 56
#define B_R  60
#define B_H  64

__device__ __forceinline__ float exp_tanh(float x) {   // exact-ish, LUT fill only
    float e = __builtin_amdgcn_exp2f(x * 2.8853900817779268f);
    return 1.0f - 2.0f * __builtin_amdgcn_rcpf(e + 1.0f);
}

__device__ __forceinline__ float fast_sigmoid(float x) {
    float e = __builtin_amdgcn_exp2f(x * -1.4426950408889634f);
    return __builtin_amdgcn_rcpf(1.0f + e);
}

// ---------------- pass 1: per-feature sum / sumsq over all rows ----------------
__global__ __launch_bounds__(256) void bn_stats(const float* __restrict__ x,
                                                float* __restrict__ ws) {
    const int tid = blockIdx.x * 256 + threadIdx.x;   // 0..262143 (1024 blocks)
    float s[8], q[8];
#pragma unroll
    for (int c = 0; c < 8; ++c) { s[c] = 0.f; q[c] = 0.f; }
    const float4* x4 = (const float4*)x;
#pragma unroll
    for (int k = 0; k < 4; ++k) {
        int r = tid + k * 262144;
        float4 a = x4[2 * r];
        float4 b = x4[2 * r + 1];
        s[0] += a.x; s[1] += a.y; s[2] += a.z; s[3] += a.w;
        s[4] += b.x; s[5] += b.y; s[6] += b.z; s[7] += b.w;
        q[0] += a.x * a.x; q[1] += a.y * a.y; q[2] += a.z * a.z; q[3] += a.w * a.w;
        q[4] += b.x * b.x; q[5] += b.y * b.y; q[6] += b.z * b.z; q[7] += b.w * b.w;
    }
#pragma unroll
    for (int off = 32; off > 0; off >>= 1) {
#pragma unroll
        for (int c = 0; c < 8; ++c) {
            s[c] += __shfl_down(s[c], off);
            q[c] += __shfl_down(q[c], off);
        }
    }
    __shared__ float red[4][16];
    const int lane = threadIdx.x & 63;
    const int wave = threadIdx.x >> 6;
    if (lane == 0) {
#pragma unroll
        for (int c = 0; c < 8; ++c) { red[wave][c] = s[c]; red[wave][8 + c] = q[c]; }
    }
    __syncthreads();
    if (threadIdx.x < 16) {
        float acc = red[0][threadIdx.x] + red[1][threadIdx.x] +
                    red[2][threadIdx.x] + red[3][threadIdx.x];
        atomicAdd(&ws[threadIdx.x], acc);
    }
}

// ---------------- pass 1.5: fold BN into L1, pack all weights to f16x2 ---------
template<int DIN, int DOUT>
__device__ void pack_layer(const float* __restrict__ w, const float* __restrict__ b,
                           uint32_t* __restrict__ wdst, float* __restrict__ bdst,
                           const float* sc, const float* sh, bool fold) {
    for (int idx = threadIdx.x; idx < DOUT * (DIN / 2); idx += blockDim.x) {
        int j = idx / (DIN / 2), i2 = idx % (DIN / 2);
        float w0 = w[(2 * i2) * DOUT + j];
        float w1 = w[(2 * i2 + 1) * DOUT + j];
        if (fold) { w0 *= sc[2 * i2]; w1 *= sc[2 * i2 + 1]; }
        h2 h; h.x = (__fp16)w0; h.y = (__fp16)w1;
        wdst[j * (DIN / 2) + i2] = __builtin_bit_cast(uint32_t, h);
    }
    for (int j = threadIdx.x; j < DOUT; j += blockDim.x) {
        float bb = b[j];
        if (fold) {
#pragma unroll
            for (int i = 0; i < 8; ++i) bb += sh[i] * w[i * DOUT + j];
        }
        bdst[j] = bb;
    }
}

__global__ __launch_bounds__(256) void prep(
    float* __restrict__ ws,
    const float* __restrict__ bn_g, const float* __restrict__ bn_b,
    const float* __restrict__ w_fm, const float* __restrict__ b_fm,
    const float* __restrict__ w_c1, const float* __restrict__ b_c1,
    const float* __restrict__ w_p1, const float* __restrict__ b_p1,
    const float* __restrict__ w_c2, const float* __restrict__ b_c2,
    const float* __restrict__ w_p2, const float* __restrict__ b_p2,
    const float* __restrict__ w_c3, const float* __restrict__ b_c3,
    const float* __restrict__ w_r,  const float* __restrict__ b_r,
    const float* __restrict__ w_h,  const float* __restrict__ b_h)
{
    const float invB = 1.0f / (float)B_ROWS;
    float sc[8], sh[8];
#pragma unroll
    for (int c = 0; c < 8; ++c) {
        float mu  = ws[c] * invB;
        float var = fmaf(-mu, mu, ws[8 + c] * invB);
        float s   = bn_g[c] * rsqrtf(var + 1e-5f);
        sc[c] = s;
        sh[c] = fmaf(-mu, s, bn_b[c]);
    }
    uint32_t* wpk = (uint32_t*)(ws + WPK_OFF);
    float*    bpk = ws + BIA_OFF;
    pack_layer<8, 16>(w_fm, b_fm, wpk + W_FM, bpk + B_FM, sc, sh, true);
    pack_layer<16,16>(w_c1, b_c1, wpk + W_C1, bpk + B_C1, sc, sh, false);
    pack_layer<16,12>(w_p1, b_p1, wpk + W_P1, bpk + B_P1, sc, sh, false);
    pack_layer<12, 8>(w_c2, b_c2, wpk + W_C2, bpk + B_C2, sc, sh, false);
    pack_layer<8,  4>(w_p2, b_p2, wpk + W_P2, bpk + B_P2, sc, sh, false);
    pack_layer<4,  4>(w_c3, b_c3, wpk + W_C3, bpk + B_C3, sc, sh, false);
    pack_layer<4,  4>(w_r,  b_r,  wpk + W_R,  bpk + B_R,  sc, sh, false);
    pack_layer<4,  1>(w_h,  b_h,  wpk + W_H,  bpk + B_H,  sc, sh, false);
}

// ---------------- LDS tanh LUT: 1024 intervals on [-4,4], base+delta ----------
__device__ __forceinline__ float lut_tanh(float x, const float2* __restrict__ lut) {
    float t  = fmaf(x, 128.0f, 512.0f);                      // [-4,4] -> [0,1024]
    t = __builtin_amdgcn_fmed3f(t, 0.0f, 1023.998f);         // clamp (handles |x|>4)
    float fl = floorf(t);
    float fr = t - fl;
    float2 e = lut[(int)fl];                                  // ds_read_b64
    return fmaf(e.y, fr, e.x);
}

// ---------------- dot2 dual-row layer: f16 inputs, f32 accumulate --------------
template<int DIN, int DOUT>
__device__ __forceinline__ void layer_dot(const h2* __restrict__ apkA, const h2* __restrict__ apkB,
                                          float* __restrict__ outA, float* __restrict__ outB,
                                          const uint32_t* __restrict__ wpk,
                                          const float* __restrict__ bias) {
#pragma unroll
    for (int j = 0; j < DOUT; ++j) {
        float accA = bias[j];
        float accB = accA;
#pragma unroll
        for (int i2 = 0; i2 < DIN / 2; ++i2) {
            h2 w = __builtin_bit_cast(h2, wpk[j * (DIN / 2) + i2]);  // one s_load, two dot2
            accA = __builtin_amdgcn_fdot2(apkA[i2], w, accA, false);
            accB = __builtin_amdgcn_fdot2(apkB[i2], w, accB, false);
        }
        outA[j] = accA;
        outB[j] = accB;
    }
}

template<int N>   // tanh via LUT, pack both rows to f16 pairs
__device__ __forceinline__ void tanh_pack(const float* __restrict__ inA, const float* __restrict__ inB,
                                          h2* __restrict__ pkA, h2* __restrict__ pkB,
                                          const float2* __restrict__ lut) {
#pragma unroll
    for (int k = 0; k < N / 2; ++k) {
        float a0 = lut_tanh(inA[2 * k], lut);
        float a1 = lut_tanh(inA[2 * k + 1], lut);
        float b0 = lut_tanh(inB[2 * k], lut);
        float b1 = lut_tanh(inB[2 * k + 1], lut);
        pkA[k] = __builtin_amdgcn_cvt_pkrtz(a0, a1);
        pkB[k] = __builtin_amdgcn_cvt_pkrtz(b0, b1);
    }
}

// ---------------- pass 2: MLP chain, 2 rows/thread, LDS-LUT tanh ---------------
__global__ __launch_bounds__(256) void qcnn_main(
    const float* __restrict__ x,
    const float* __restrict__ ws, float* __restrict__ out)
{
    __shared__ float2 lut[1024];
    // fill: 4 intervals per thread, h = 1/128
    {
        const float h = 0.0078125f;
#pragma unroll
        for (int k = 0; k < 4; ++k) {
            int i = threadIdx.x + k * 256;
            float x0 = fmaf((float)i, h, -4.0f);
            float t0 = exp_tanh(x0);
            float t1 = exp_tanh(x0 + h);
            lut[i] = make_float2(t0, t1 - t0);
        }
    }
    __syncthreads();

    const uint32_t* wpk = (const uint32_t*)(ws + WPK_OFF);
    const float*    bpk = ws + BIA_OFF;

    const int tid = blockIdx.x * 256 + threadIdx.x;   // 0..524287
    const int r0 = tid, r1 = tid + (B_ROWS / 2);
    const float4* x4 = (const float4*)x;
    float4 xa0 = x4[2 * r0], xa1 = x4[2 * r0 + 1];
    float4 xb0 = x4[2 * r1], xb1 = x4[2 * r1 + 1];

    // BN folded into L1 weights -> pack raw x
    h2 a8[4], b8[4];
    a8[0] = __builtin_amdgcn_cvt_pkrtz(xa0.x, xa0.y);
    a8[1] = __builtin_amdgcn_cvt_pkrtz(xa0.z, xa0.w);
    a8[2] = __builtin_amdgcn_cvt_pkrtz(xa1.x, xa1.y);
    a8[3] = __builtin_amdgcn_cvt_pkrtz(xa1.z, xa1.w);
    b8[0] = __builtin_amdgcn_cvt_pkrtz(xb0.x, xb0.y);
    b8[1] = __builtin_amdgcn_cvt_pkrtz(xb0.z, xb0.w);
    b8[2] = __builtin_amdgcn_cvt_pkrtz(xb1.x, xb1.y);
    b8[3] = __builtin_amdgcn_cvt_pkrtz(xb1.z, xb1.w);

    float oA[16], oB[16]; h2 pA[8], pB[8];
    layer_dot<8, 16>(a8, b8, oA, oB, wpk + W_FM, bpk + B_FM);
    tanh_pack<16>(oA, oB, pA, pB, lut);
    float o2A[16], o2B[16]; h2 p2A[8], p2B[8];
    layer_dot<16,16>(pA, pB, o2A, o2B, wpk + W_C1, bpk + B_C1);
    tanh_pack<16>(o2A, o2B, p2A, p2B, lut);
    float o3A[12], o3B[12]; h2 p3A[6], p3B[6];
    layer_dot<16,12>(p2A, p2B, o3A, o3B, wpk + W_P1, bpk + B_P1);
    tanh_pack<12>(o3A, o3B, p3A, p3B, lut);
    float o4A[8], o4B[8]; h2 p4A[4], p4B[4];
    layer_dot<12, 8>(p3A, p3B, o4A, o4B, wpk + W_C2, bpk + B_C2);
    tanh_pack<8>(o4A, o4B, p4A, p4B, lut);
    float o5A[4], o5B[4]; h2 p5A[2], p5B[2];
    layer_dot<8,  4>(p4A, p4B, o5A, o5B, wpk + W_P2, bpk + B_P2);
    tanh_pack<4>(o5A, o5B, p5A, p5B, lut);
    float c4A[4], c4B[4];
    layer_dot<4,  4>(p5A, p5B, c4A, c4B, wpk + W_C3, bpk + B_C3);
#pragma unroll
    for (int j = 0; j < 4; ++j) {
        c4A[j] = lut_tanh(c4A[j], lut);
        c4B[j] = lut_tanh(c4B[j], lut);
    }
    h2 pcA[2], pcB[2];
    pcA[0] = __builtin_amdgcn_cvt_pkrtz(c4A[0], c4A[1]);
    pcA[1] = __builtin_amdgcn_cvt_pkrtz(c4A[2], c4A[3]);
    pcB[0] = __builtin_amdgcn_cvt_pkrtz(c4B[0], c4B[1]);
    pcB[1] = __builtin_amdgcn_cvt_pkrtz(c4B[2], c4B[3]);
    float r4A[4], r4B[4];
    layer_dot<4,  4>(pcA, pcB, r4A, r4B, wpk + W_R, bpk + B_R);
#pragma unroll
    for (int j = 0; j < 4; ++j) {
        c4A[j] += fmaxf(r4A[j], 0.f);
        c4B[j] += fmaxf(r4B[j], 0.f);
    }
    h2 phA[2], phB[2];
    phA[0] = __builtin_amdgcn_cvt_pkrtz(c4A[0], c4A[1]);
    phA[1] = __builtin_amdgcn_cvt_pkrtz(c4A[2], c4A[3]);
    phB[0] = __builtin_amdgcn_cvt_pkrtz(c4B[0], c4B[1]);
    phB[1] = __builtin_amdgcn_cvt_pkrtz(c4B[2], c4B[3]);
    float ohA[1], ohB[1];
    layer_dot<4,  1>(phA, phB, ohA, ohB, wpk + W_H, bpk + B_H);
    out[r0] = fast_sigmoid(ohA[0]);
    out[r1] = fast_sigmoid(ohB[0]);
}

extern "C" void kernel_launch(void* const* d_in, const int* in_sizes, int n_in,
                              void* d_out, int out_size, void* d_ws, size_t ws_size,
                              hipStream_t stream) {
    const float* x    = (const float*)d_in[0];
    const float* bn_g = (const float*)d_in[1];
    const float* bn_b = (const float*)d_in[2];
    const float* w_fm = (const float*)d_in[3];
    const float* b_fm = (const float*)d_in[4];
    const float* w_c1 = (const float*)d_in[5];
    const float* b_c1 = (const float*)d_in[6];
    const float* w_p1 = (const float*)d_in[7];
    const float* b_p1 = (const float*)d_in[8];
    const float* w_c2 = (const float*)d_in[9];
    const float* b_c2 = (const float*)d_in[10];
    const float* w_p2 = (const float*)d_in[11];
    const float* b_p2 = (const float*)d_in[12];
    const float* w_c3 = (const float*)d_in[13];
    const float* b_c3 = (const float*)d_in[14];
    const float* w_r  = (const float*)d_in[15];
    const float* b_r  = (const float*)d_in[16];
    const float* w_h  = (const float*)d_in[17];
    const float* b_h  = (const float*)d_in[18];
    float* out = (float*)d_out;
    float* ws  = (float*)d_ws;

    (void)hipMemsetAsync(d_ws, 0, 16 * sizeof(float), stream);
    bn_stats<<<1024, 256, 0, stream>>>(x, ws);
    prep<<<1, 256, 0, stream>>>(ws, bn_g, bn_b, w_fm, b_fm, w_c1, b_c1, w_p1, b_p1,
                                w_c2, b_c2, w_p2, b_p2, w_c3, b_c3, w_r, b_r, w_h, b_h);
    qcnn_main<<<MAIN_BLOCKS, 256, 0, stream>>>(x, ws, out);
}

// Round 6
// 146.613 us; speedup vs baseline: 1.0592x; 1.0459x over previous
//
#include <hip/hip_runtime.h>
#include <stdint.h>

#define B_ROWS 1048576
#define ROWS_PER_THREAD 2
#define MAIN_BLOCKS (B_ROWS / (256 * ROWS_PER_THREAD))   // 2048
#define STAT_BLOCKS 1024

typedef __fp16 h2 __attribute__((ext_vector_type(2)));

// ws float layout:
//  [0..15]        (unused)
//  [16..16399]    per-block bn partials: 1024 blocks x 16 floats (sum[8],sumsq[8])
//  [16400..16769] packed f16x2 weights (as uint32), 370 dwords
//  [16770..16834] f32 biases, 65 floats
#define PART_OFF 16
#define WPK_OFF 16400
#define BIA_OFF 16770
#define W_FM 0
#define W_C1 64
#define W_P1 192
#define W_C2 288
#define W_P2 336
#define W_C3 352
#define W_R  360
#define W_H  368
#define B_FM 0
#define B_C1 16
#define B_P1 32
#define B_C2 44
#define B_P2 52
#define B_C3 56
#define B_R  60
#define B_H  64

__device__ __forceinline__ float exp_tanh(float x) {   // exact-ish, LUT fill only
    float e = __builtin_amdgcn_exp2f(x * 2.8853900817779268f);
    return 1.0f - 2.0f * __builtin_amdgcn_rcpf(e + 1.0f);
}

__device__ __forceinline__ float fast_sigmoid(float x) {
    float e = __builtin_amdgcn_exp2f(x * -1.4426950408889634f);
    return __builtin_amdgcn_rcpf(1.0f + e);
}

// ---------------- pass 1: per-block partial sum / sumsq (no atomics) -----------
__global__ __launch_bounds__(256) void bn_stats(const float* __restrict__ x,
                                                float* __restrict__ ws) {
    const int tid = blockIdx.x * 256 + threadIdx.x;   // 0..262143
    float s[8], q[8];
#pragma unroll
    for (int c = 0; c < 8; ++c) { s[c] = 0.f; q[c] = 0.f; }
    const float4* x4 = (const float4*)x;
#pragma unroll
    for (int k = 0; k < 4; ++k) {
        int r = tid + k * 262144;
        float4 a = x4[2 * r];
        float4 b = x4[2 * r + 1];
        s[0] += a.x; s[1] += a.y; s[2] += a.z; s[3] += a.w;
        s[4] += b.x; s[5] += b.y; s[6] += b.z; s[7] += b.w;
        q[0] += a.x * a.x; q[1] += a.y * a.y; q[2] += a.z * a.z; q[3] += a.w * a.w;
        q[4] += b.x * b.x; q[5] += b.y * b.y; q[6] += b.z * b.z; q[7] += b.w * b.w;
    }
#pragma unroll
    for (int off = 32; off > 0; off >>= 1) {
#pragma unroll
        for (int c = 0; c < 8; ++c) {
            s[c] += __shfl_down(s[c], off);
            q[c] += __shfl_down(q[c], off);
        }
    }
    __shared__ float red[4][16];
    const int lane = threadIdx.x & 63;
    const int wave = threadIdx.x >> 6;
    if (lane == 0) {
#pragma unroll
        for (int c = 0; c < 8; ++c) { red[wave][c] = s[c]; red[wave][8 + c] = q[c]; }
    }
    __syncthreads();
    if (threadIdx.x < 16) {
        float acc = red[0][threadIdx.x] + red[1][threadIdx.x] +
                    red[2][threadIdx.x] + red[3][threadIdx.x];
        ws[PART_OFF + blockIdx.x * 16 + threadIdx.x] = acc;   // plain store
    }
}

// ---------------- pass 1.5: reduce partials, fold BN, pack weights -------------
template<int DIN, int DOUT>
__device__ void pack_layer(const float* __restrict__ w, const float* __restrict__ b,
                           uint32_t* __restrict__ wdst, float* __restrict__ bdst,
                           const float* sc, const float* sh, bool fold) {
    for (int idx = threadIdx.x; idx < DOUT * (DIN / 2); idx += blockDim.x) {
        int j = idx / (DIN / 2), i2 = idx % (DIN / 2);
        float w0 = w[(2 * i2) * DOUT + j];
        float w1 = w[(2 * i2 + 1) * DOUT + j];
        if (fold) { w0 *= sc[2 * i2]; w1 *= sc[2 * i2 + 1]; }
        h2 h; h.x = (__fp16)w0; h.y = (__fp16)w1;
        wdst[j * (DIN / 2) + i2] = __builtin_bit_cast(uint32_t, h);
    }
    for (int j = threadIdx.x; j < DOUT; j += blockDim.x) {
        float bb = b[j];
        if (fold) {
#pragma unroll
            for (int i = 0; i < 8; ++i) bb += sh[i] * w[i * DOUT + j];
        }
        bdst[j] = bb;
    }
}

__global__ __launch_bounds__(256) void prep(
    float* __restrict__ ws,
    const float* __restrict__ bn_g, const float* __restrict__ bn_b,
    const float* __restrict__ w_fm, const float* __restrict__ b_fm,
    const float* __restrict__ w_c1, const float* __restrict__ b_c1,
    const float* __restrict__ w_p1, const float* __restrict__ b_p1,
    const float* __restrict__ w_c2, const float* __restrict__ b_c2,
    const float* __restrict__ w_p2, const float* __restrict__ b_p2,
    const float* __restrict__ w_c3, const float* __restrict__ b_c3,
    const float* __restrict__ w_r,  const float* __restrict__ b_r,
    const float* __restrict__ w_h,  const float* __restrict__ b_h)
{
    // reduce 1024 x 16 partials: thread = (chunk 0..15, feat 0..15)
    __shared__ float acc[16][17];
    __shared__ float scs[8], shs[8];
    {
        const int f = threadIdx.x & 15;
        const int chunk = threadIdx.x >> 4;
        float a = 0.f;
        const float* p = ws + PART_OFF + (chunk * 64) * 16 + f;
#pragma unroll 8
        for (int b = 0; b < 64; ++b) a += p[b * 16];
        acc[chunk][f] = a;
    }
    __syncthreads();
    if (threadIdx.x < 16) {
        float t = 0.f;
#pragma unroll
        for (int c = 0; c < 16; ++c) t += acc[c][threadIdx.x];
        acc[16 - 16][threadIdx.x] = t;   // acc[0][f] = final stat f
    }
    __syncthreads();
    if (threadIdx.x < 8) {
        const float invB = 1.0f / (float)B_ROWS;
        int c = threadIdx.x;
        float mu  = acc[0][c] * invB;
        float var = fmaf(-mu, mu, acc[0][8 + c] * invB);
        float s   = bn_g[c] * rsqrtf(var + 1e-5f);
        scs[c] = s;
        shs[c] = fmaf(-mu, s, bn_b[c]);
    }
    __syncthreads();
    uint32_t* wpk = (uint32_t*)(ws + WPK_OFF);
    float*    bpk = ws + BIA_OFF;
    pack_layer<8, 16>(w_fm, b_fm, wpk + W_FM, bpk + B_FM, scs, shs, true);
    pack_layer<16,16>(w_c1, b_c1, wpk + W_C1, bpk + B_C1, scs, shs, false);
    pack_layer<16,12>(w_p1, b_p1, wpk + W_P1, bpk + B_P1, scs, shs, false);
    pack_layer<12, 8>(w_c2, b_c2, wpk + W_C2, bpk + B_C2, scs, shs, false);
    pack_layer<8,  4>(w_p2, b_p2, wpk + W_P2, bpk + B_P2, scs, shs, false);
    pack_layer<4,  4>(w_c3, b_c3, wpk + W_C3, bpk + B_C3, scs, shs, false);
    pack_layer<4,  4>(w_r,  b_r,  wpk + W_R,  bpk + B_R,  scs, shs, false);
    pack_layer<4,  1>(w_h,  b_h,  wpk + W_H,  bpk + B_H,  scs, shs, false);
}

// ---------------- LDS tanh LUT: 1024 intervals on [-4,4], base+delta ----------
__device__ __forceinline__ float lut_tanh(float x, const float2* __restrict__ lut) {
    float t  = fmaf(x, 128.0f, 512.0f);                      // [-4,4] -> [0,1024]
    t = __builtin_amdgcn_fmed3f(t, 0.0f, 1023.998f);         // clamp (handles |x|>4)
    float fl = floorf(t);
    float fr = t - fl;
    float2 e = lut[(int)fl];                                  // ds_read_b64
    return fmaf(e.y, fr, e.x);
}

// ---------------- dot2 dual-row layer: f16 inputs, f32 accumulate --------------
template<int DIN, int DOUT>
__device__ __forceinline__ void layer_dot(const h2* __restrict__ apkA, const h2* __restrict__ apkB,
                                          float* __restrict__ outA, float* __restrict__ outB,
                                          const uint32_t* __restrict__ wpk,
                                          const float* __restrict__ bias) {
#pragma unroll
    for (int j = 0; j < DOUT; ++j) {
        float accA = bias[j];
        float accB = accA;
#pragma unroll
        for (int i2 = 0; i2 < DIN / 2; ++i2) {
            h2 w = __builtin_bit_cast(h2, wpk[j * (DIN / 2) + i2]);  // one s_load, two dot2
            accA = __builtin_amdgcn_fdot2(apkA[i2], w, accA, false);
            accB = __builtin_amdgcn_fdot2(apkB[i2], w, accB, false);
        }
        outA[j] = accA;
        outB[j] = accB;
    }
}

template<int N>   // tanh via LUT, pack both rows to f16 pairs
__device__ __forceinline__ void tanh_pack(const float* __restrict__ inA, const float* __restrict__ inB,
                                          h2* __restrict__ pkA, h2* __restrict__ pkB,
                                          const float2* __restrict__ lut) {
#pragma unroll
    for (int k = 0; k < N / 2; ++k) {
        float a0 = lut_tanh(inA[2 * k], lut);
        float a1 = lut_tanh(inA[2 * k + 1], lut);
        float b0 = lut_tanh(inB[2 * k], lut);
        float b1 = lut_tanh(inB[2 * k + 1], lut);
        pkA[k] = __builtin_amdgcn_cvt_pkrtz(a0, a1);
        pkB[k] = __builtin_amdgcn_cvt_pkrtz(b0, b1);
    }
}

// ---------------- pass 2: MLP chain, 2 rows/thread, LDS-LUT tanh ---------------
__global__ __launch_bounds__(256) void qcnn_main(
    const float* __restrict__ x,
    const float* __restrict__ ws, float* __restrict__ out)
{
    // issue x loads FIRST so HBM latency overlaps LUT fill + barrier
    const int tid = blockIdx.x * 256 + threadIdx.x;   // 0..524287
    const int r0 = tid, r1 = tid + (B_ROWS / 2);
    const float4* x4 = (const float4*)x;
    float4 xa0 = x4[2 * r0], xa1 = x4[2 * r0 + 1];
    float4 xb0 = x4[2 * r1], xb1 = x4[2 * r1 + 1];

    __shared__ float2 lut[1024];
    {
        const float h = 0.0078125f;
#pragma unroll
        for (int k = 0; k < 4; ++k) {
            int i = threadIdx.x + k * 256;
            float x0 = fmaf((float)i, h, -4.0f);
            float t0 = exp_tanh(x0);
            float t1 = exp_tanh(x0 + h);
            lut[i] = make_float2(t0, t1 - t0);
        }
    }
    __syncthreads();

    const uint32_t* wpk = (const uint32_t*)(ws + WPK_OFF);
    const float*    bpk = ws + BIA_OFF;

    // BN folded into L1 weights -> pack raw x
    h2 a8[4], b8[4];
    a8[0] = __builtin_amdgcn_cvt_pkrtz(xa0.x, xa0.y);
    a8[1] = __builtin_amdgcn_cvt_pkrtz(xa0.z, xa0.w);
    a8[2] = __builtin_amdgcn_cvt_pkrtz(xa1.x, xa1.y);
    a8[3] = __builtin_amdgcn_cvt_pkrtz(xa1.z, xa1.w);
    b8[0] = __builtin_amdgcn_cvt_pkrtz(xb0.x, xb0.y);
    b8[1] = __builtin_amdgcn_cvt_pkrtz(xb0.z, xb0.w);
    b8[2] = __builtin_amdgcn_cvt_pkrtz(xb1.x, xb1.y);
    b8[3] = __builtin_amdgcn_cvt_pkrtz(xb1.z, xb1.w);

    float oA[16], oB[16]; h2 pA[8], pB[8];
    layer_dot<8, 16>(a8, b8, oA, oB, wpk + W_FM, bpk + B_FM);
    tanh_pack<16>(oA, oB, pA, pB, lut);
    float o2A[16], o2B[16]; h2 p2A[8], p2B[8];
    layer_dot<16,16>(pA, pB, o2A, o2B, wpk + W_C1, bpk + B_C1);
    tanh_pack<16>(o2A, o2B, p2A, p2B, lut);
    float o3A[12], o3B[12]; h2 p3A[6], p3B[6];
    layer_dot<16,12>(p2A, p2B, o3A, o3B, wpk + W_P1, bpk + B_P1);
    tanh_pack<12>(o3A, o3B, p3A, p3B, lut);
    float o4A[8], o4B[8]; h2 p4A[4], p4B[4];
    layer_dot<12, 8>(p3A, p3B, o4A, o4B, wpk + W_C2, bpk + B_C2);
    tanh_pack<8>(o4A, o4B, p4A, p4B, lut);
    float o5A[4], o5B[4]; h2 p5A[2], p5B[2];
    layer_dot<8,  4>(p4A, p4B, o5A, o5B, wpk + W_P2, bpk + B_P2);
    tanh_pack<4>(o5A, o5B, p5A, p5B, lut);
    float c4A[4], c4B[4];
    layer_dot<4,  4>(p5A, p5B, c4A, c4B, wpk + W_C3, bpk + B_C3);
#pragma unroll
    for (int j = 0; j < 4; ++j) {
        c4A[j] = lut_tanh(c4A[j], lut);
        c4B[j] = lut_tanh(c4B[j], lut);
    }
    h2 pcA[2], pcB[2];
    pcA[0] = __builtin_amdgcn_cvt_pkrtz(c4A[0], c4A[1]);
    pcA[1] = __builtin_amdgcn_cvt_pkrtz(c4A[2], c4A[3]);
    pcB[0] = __builtin_amdgcn_cvt_pkrtz(c4B[0], c4B[1]);
    pcB[1] = __builtin_amdgcn_cvt_pkrtz(c4B[2], c4B[3]);
    float r4A[4], r4B[4];
    layer_dot<4,  4>(pcA, pcB, r4A, r4B, wpk + W_R, bpk + B_R);
#pragma unroll
    for (int j = 0; j < 4; ++j) {
        c4A[j] += fmaxf(r4A[j], 0.f);
        c4B[j] += fmaxf(r4B[j], 0.f);
    }
    h2 phA[2], phB[2];
    phA[0] = __builtin_amdgcn_cvt_pkrtz(c4A[0], c4A[1]);
    phA[1] = __builtin_amdgcn_cvt_pkrtz(c4A[2], c4A[3]);
    phB[0] = __builtin_amdgcn_cvt_pkrtz(c4B[0], c4B[1]);
    phB[1] = __builtin_amdgcn_cvt_pkrtz(c4B[2], c4B[3]);
    float ohA[1], ohB[1];
    layer_dot<4,  1>(phA, phB, ohA, ohB, wpk + W_H, bpk + B_H);
    out[r0] = fast_sigmoid(ohA[0]);
    out[r1] = fast_sigmoid(ohB[0]);
}

extern "C" void kernel_launch(void* const* d_in, const int* in_sizes, int n_in,
                              void* d_out, int out_size, void* d_ws, size_t ws_size,
                              hipStream_t stream) {
    const float* x    = (const float*)d_in[0];
    const float* bn_g = (const float*)d_in[1];
    const float* bn_b = (const float*)d_in[2];
    const float* w_fm = (const float*)d_in[3];
    const float* b_fm = (const float*)d_in[4];
    const float* w_c1 = (const float*)d_in[5];
    const float* b_c1 = (const float*)d_in[6];
    const float* w_p1 = (const float*)d_in[7];
    const float* b_p1 = (const float*)d_in[8];
    const float* w_c2 = (const float*)d_in[9];
    const float* b_c2 = (const float*)d_in[10];
    const float* w_p2 = (const float*)d_in[11];
    const float* b_p2 = (const float*)d_in[12];
    const float* w_c3 = (const float*)d_in[13];
    const float* b_c3 = (const float*)d_in[14];
    const float* w_r  = (const float*)d_in[15];
    const float* b_r  = (const float*)d_in[16];
    const float* w_h  = (const float*)d_in[17];
    const float* b_h  = (const float*)d_in[18];
    float* out = (float*)d_out;
    float* ws  = (float*)d_ws;

    bn_stats<<<STAT_BLOCKS, 256, 0, stream>>>(x, ws);
    prep<<<1, 256, 0, stream>>>(ws, bn_g, bn_b, w_fm, b_fm, w_c1, b_c1, w_p1, b_p1,
                                w_c2, b_c2, w_p2, b_p2, w_c3, b_c3, w_r, b_r, w_h, b_h);
    qcnn_main<<<MAIN_BLOCKS, 256, 0, stream>>>(x, ws, out);
}

// Round 7
// 143.058 us; speedup vs baseline: 1.0855x; 1.0248x over previous
//
#include <hip/hip_runtime.h>
#include <stdint.h>

#define B_ROWS 1048576
#define STAT_BLOCKS 512
#define MAIN_BLOCKS 2048            // 256 thr x 2 rows

typedef __fp16 h2 __attribute__((ext_vector_type(2)));

// ws float layout:
//  [16 .. 16+8192)       per-block bn partials: 512 blocks x 16 floats
//  [8208 .. 8578)        packed f16x2 weights (uint32), 370 dwords  (raw, no BN fold)
//  [8578 .. 8643)        f32 biases, 65 floats
#define PART_OFF 16
#define WPK_OFF 8208
#define BIA_OFF 8578
#define W_FM 0
#define W_C1 64
#define W_P1 192
#define W_C2 288
#define W_P2 336
#define W_C3 352
#define W_R  360
#define W_H  368
#define B_FM 0
#define B_C1 16
#define B_P1 32
#define B_C2 44
#define B_P2 52
#define B_C3 56
#define B_R  60
#define B_H  64

__device__ __forceinline__ float exp_tanh(float x) {   // LUT fill only
    float e = __builtin_amdgcn_exp2f(x * 2.8853900817779268f);
    return 1.0f - 2.0f * __builtin_amdgcn_rcpf(e + 1.0f);
}

__device__ __forceinline__ float fast_sigmoid(float x) {
    float e = __builtin_amdgcn_exp2f(x * -1.4426950408889634f);
    return __builtin_amdgcn_rcpf(1.0f + e);
}

// ---- raw weight packing (no BN fold), used by bn_stats block 0 ----------------
template<int DIN, int DOUT>
__device__ void pack_layer(const float* __restrict__ w, const float* __restrict__ b,
                           uint32_t* __restrict__ wdst, float* __restrict__ bdst) {
    for (int idx = threadIdx.x; idx < DOUT * (DIN / 2); idx += blockDim.x) {
        int j = idx / (DIN / 2), i2 = idx % (DIN / 2);
        h2 h;
        h.x = (__fp16)w[(2 * i2) * DOUT + j];
        h.y = (__fp16)w[(2 * i2 + 1) * DOUT + j];
        wdst[j * (DIN / 2) + i2] = __builtin_bit_cast(uint32_t, h);
    }
    for (int j = threadIdx.x; j < DOUT; j += blockDim.x) bdst[j] = b[j];
}

// ---------------- pass 1: partials (512 blocks) + block0 packs weights ---------
__global__ __launch_bounds__(256) void bn_stats(
    const float* __restrict__ x, float* __restrict__ ws,
    const float* __restrict__ w_fm, const float* __restrict__ b_fm,
    const float* __restrict__ w_c1, const float* __restrict__ b_c1,
    const float* __restrict__ w_p1, const float* __restrict__ b_p1,
    const float* __restrict__ w_c2, const float* __restrict__ b_c2,
    const float* __restrict__ w_p2, const float* __restrict__ b_p2,
    const float* __restrict__ w_c3, const float* __restrict__ b_c3,
    const float* __restrict__ w_r,  const float* __restrict__ b_r,
    const float* __restrict__ w_h,  const float* __restrict__ b_h)
{
    const int tid = blockIdx.x * 256 + threadIdx.x;   // 0..131071
    float s[8], q[8];
#pragma unroll
    for (int c = 0; c < 8; ++c) { s[c] = 0.f; q[c] = 0.f; }
    const float4* x4 = (const float4*)x;
#pragma unroll
    for (int k = 0; k < 8; ++k) {
        int r = tid + k * 131072;
        float4 a = x4[2 * r];
        float4 b = x4[2 * r + 1];
        s[0] += a.x; s[1] += a.y; s[2] += a.z; s[3] += a.w;
        s[4] += b.x; s[5] += b.y; s[6] += b.z; s[7] += b.w;
        q[0] += a.x * a.x; q[1] += a.y * a.y; q[2] += a.z * a.z; q[3] += a.w * a.w;
        q[4] += b.x * b.x; q[5] += b.y * b.y; q[6] += b.z * b.z; q[7] += b.w * b.w;
    }
#pragma unroll
    for (int off = 32; off > 0; off >>= 1) {
#pragma unroll
        for (int c = 0; c < 8; ++c) {
            s[c] += __shfl_down(s[c], off);
            q[c] += __shfl_down(q[c], off);
        }
    }
    __shared__ float red[4][16];
    const int lane = threadIdx.x & 63;
    const int wave = threadIdx.x >> 6;
    if (lane == 0) {
#pragma unroll
        for (int c = 0; c < 8; ++c) { red[wave][c] = s[c]; red[wave][8 + c] = q[c]; }
    }
    __syncthreads();
    if (threadIdx.x < 16) {
        float acc = red[0][threadIdx.x] + red[1][threadIdx.x] +
                    red[2][threadIdx.x] + red[3][threadIdx.x];
        ws[PART_OFF + blockIdx.x * 16 + threadIdx.x] = acc;   // plain store
    }
    // block 0: pack all weights (independent of stats)
    if (blockIdx.x == 0) {
        uint32_t* wpk = (uint32_t*)(ws + WPK_OFF);
        float*    bpk = ws + BIA_OFF;
        pack_layer<8, 16>(w_fm, b_fm, wpk + W_FM, bpk + B_FM);
        pack_layer<16,16>(w_c1, b_c1, wpk + W_C1, bpk + B_C1);
        pack_layer<16,12>(w_p1, b_p1, wpk + W_P1, bpk + B_P1);
        pack_layer<12, 8>(w_c2, b_c2, wpk + W_C2, bpk + B_C2);
        pack_layer<8,  4>(w_p2, b_p2, wpk + W_P2, bpk + B_P2);
        pack_layer<4,  4>(w_c3, b_c3, wpk + W_C3, bpk + B_C3);
        pack_layer<4,  4>(w_r,  b_r,  wpk + W_R,  bpk + B_R);
        pack_layer<4,  1>(w_h,  b_h,  wpk + W_H,  bpk + B_H);
    }
}

// ---------------- LDS tanh LUT: 1024 intervals on [-4,4], base+delta ----------
__device__ __forceinline__ float lut_tanh(float x, const float2* __restrict__ lut) {
    float t  = fmaf(x, 128.0f, 512.0f);
    t = __builtin_amdgcn_fmed3f(t, 0.0f, 1023.998f);
    float fl = floorf(t);
    float fr = t - fl;
    float2 e = lut[(int)fl];
    return fmaf(e.y, fr, e.x);
}

// ---------------- dot2 dual-row layer ------------------------------------------
template<int DIN, int DOUT>
__device__ __forceinline__ void layer_dot(const h2* __restrict__ apkA, const h2* __restrict__ apkB,
                                          float* __restrict__ outA, float* __restrict__ outB,
                                          const uint32_t* __restrict__ wpk,
                                          const float* __restrict__ bias) {
#pragma unroll
    for (int j = 0; j < DOUT; ++j) {
        float accA = bias[j];
        float accB = accA;
#pragma unroll
        for (int i2 = 0; i2 < DIN / 2; ++i2) {
            h2 w = __builtin_bit_cast(h2, wpk[j * (DIN / 2) + i2]);
            accA = __builtin_amdgcn_fdot2(apkA[i2], w, accA, false);
            accB = __builtin_amdgcn_fdot2(apkB[i2], w, accB, false);
        }
        outA[j] = accA;
        outB[j] = accB;
    }
}

template<int N>
__device__ __forceinline__ void tanh_pack(const float* __restrict__ inA, const float* __restrict__ inB,
                                          h2* __restrict__ pkA, h2* __restrict__ pkB,
                                          const float2* __restrict__ lut) {
#pragma unroll
    for (int k = 0; k < N / 2; ++k) {
        float a0 = lut_tanh(inA[2 * k], lut);
        float a1 = lut_tanh(inA[2 * k + 1], lut);
        float b0 = lut_tanh(inB[2 * k], lut);
        float b1 = lut_tanh(inB[2 * k + 1], lut);
        pkA[k] = __builtin_amdgcn_cvt_pkrtz(a0, a1);
        pkB[k] = __builtin_amdgcn_cvt_pkrtz(b0, b1);
    }
}

// ---------------- pass 2: inline stats-reduce + normalize + MLP chain ----------
__global__ __launch_bounds__(256) void qcnn_main(
    const float* __restrict__ x,
    const float* __restrict__ bn_g, const float* __restrict__ bn_b,
    const float* __restrict__ ws, float* __restrict__ out)
{
    // issue x loads first (overlap prologue)
    const int tid = blockIdx.x * 256 + threadIdx.x;
    const int r0 = tid, r1 = tid + (B_ROWS / 2);
    const float4* x4 = (const float4*)x;
    float4 xa0 = x4[2 * r0], xa1 = x4[2 * r0 + 1];
    float4 xb0 = x4[2 * r1], xb1 = x4[2 * r1 + 1];

    __shared__ float2 lut[1024];
    __shared__ float accs[16][17];
    __shared__ float scs[8], shs[8];

    // LUT fill (VALU, overlaps x-load latency)
    {
        const float h = 0.0078125f;
#pragma unroll
        for (int k = 0; k < 4; ++k) {
            int i = threadIdx.x + k * 256;
            float x0 = fmaf((float)i, h, -4.0f);
            float t0 = exp_tanh(x0);
            float t1 = exp_tanh(x0 + h);
            lut[i] = make_float2(t0, t1 - t0);
        }
    }
    // per-block redundant stats reduce: 512 x 16 partials (L2-hit)
    {
        const int f = threadIdx.x & 15;
        const int chunk = threadIdx.x >> 4;          // 0..15, each sums 32 blocks
        const float* p = ws + PART_OFF + (chunk * 32) * 16 + f;
        float a = 0.f;
#pragma unroll 8
        for (int b = 0; b < 32; ++b) a += p[b * 16];
        accs[chunk][f] = a;
    }
    __syncthreads();
    if (threadIdx.x < 16) {
        float t = 0.f;
#pragma unroll
        for (int c = 0; c < 16; ++c) t += accs[c][threadIdx.x];
        accs[0][threadIdx.x] = t;
    }
    __syncthreads();
    if (threadIdx.x < 8) {
        const float invB = 1.0f / (float)B_ROWS;
        int c = threadIdx.x;
        float mu  = accs[0][c] * invB;
        float var = fmaf(-mu, mu, accs[0][8 + c] * invB);
        float s   = bn_g[c] * rsqrtf(var + 1e-5f);
        scs[c] = s;
        shs[c] = fmaf(-mu, s, bn_b[c]);
    }
    __syncthreads();

    float sc[8], sh[8];
#pragma unroll
    for (int c = 0; c < 8; ++c) { sc[c] = scs[c]; sh[c] = shs[c]; }

    const uint32_t* wpk = (const uint32_t*)(ws + WPK_OFF);
    const float*    bpk = ws + BIA_OFF;

    // normalize in f32, then quantize to f16 pairs
    float nA[8], nB[8];
    nA[0] = fmaf(xa0.x, sc[0], sh[0]); nA[1] = fmaf(xa0.y, sc[1], sh[1]);
    nA[2] = fmaf(xa0.z, sc[2], sh[2]); nA[3] = fmaf(xa0.w, sc[3], sh[3]);
    nA[4] = fmaf(xa1.x, sc[4], sh[4]); nA[5] = fmaf(xa1.y, sc[5], sh[5]);
    nA[6] = fmaf(xa1.z, sc[6], sh[6]); nA[7] = fmaf(xa1.w, sc[7], sh[7]);
    nB[0] = fmaf(xb0.x, sc[0], sh[0]); nB[1] = fmaf(xb0.y, sc[1], sh[1]);
    nB[2] = fmaf(xb0.z, sc[2], sh[2]); nB[3] = fmaf(xb0.w, sc[3], sh[3]);
    nB[4] = fmaf(xb1.x, sc[4], sh[4]); nB[5] = fmaf(xb1.y, sc[5], sh[5]);
    nB[6] = fmaf(xb1.z, sc[6], sh[6]); nB[7] = fmaf(xb1.w, sc[7], sh[7]);
    h2 a8[4], b8[4];
#pragma unroll
    for (int k = 0; k < 4; ++k) {
        a8[k] = __builtin_amdgcn_cvt_pkrtz(nA[2 * k], nA[2 * k + 1]);
        b8[k] = __builtin_amdgcn_cvt_pkrtz(nB[2 * k], nB[2 * k + 1]);
    }

    float oA[16], oB[16]; h2 pA[8], pB[8];
    layer_dot<8, 16>(a8, b8, oA, oB, wpk + W_FM, bpk + B_FM);
    tanh_pack<16>(oA, oB, pA, pB, lut);
    float o2A[16], o2B[16]; h2 p2A[8], p2B[8];
    layer_dot<16,16>(pA, pB, o2A, o2B, wpk + W_C1, bpk + B_C1);
    tanh_pack<16>(o2A, o2B, p2A, p2B, lut);
    float o3A[12], o3B[12]; h2 p3A[6], p3B[6];
    layer_dot<16,12>(p2A, p2B, o3A, o3B, wpk + W_P1, bpk + B_P1);
    tanh_pack<12>(o3A, o3B, p3A, p3B, lut);
    float o4A[8], o4B[8]; h2 p4A[4], p4B[4];
    layer_dot<12, 8>(p3A, p3B, o4A, o4B, wpk + W_C2, bpk + B_C2);
    tanh_pack<8>(o4A, o4B, p4A, p4B, lut);
    float o5A[4], o5B[4]; h2 p5A[2], p5B[2];
    layer_dot<8,  4>(p4A, p4B, o5A, o5B, wpk + W_P2, bpk + B_P2);
    tanh_pack<4>(o5A, o5B, p5A, p5B, lut);
    float c4A[4], c4B[4];
    layer_dot<4,  4>(p5A, p5B, c4A, c4B, wpk + W_C3, bpk + B_C3);
#pragma unroll
    for (int j = 0; j < 4; ++j) {
        c4A[j] = lut_tanh(c4A[j], lut);
        c4B[j] = lut_tanh(c4B[j], lut);
    }
    h2 pcA[2], pcB[2];
    pcA[0] = __builtin_amdgcn_cvt_pkrtz(c4A[0], c4A[1]);
    pcA[1] = __builtin_amdgcn_cvt_pkrtz(c4A[2], c4A[3]);
    pcB[0] = __builtin_amdgcn_cvt_pkrtz(c4B[0], c4B[1]);
    pcB[1] = __builtin_amdgcn_cvt_pkrtz(c4B[2], c4B[3]);
    float r4A[4], r4B[4];
    layer_dot<4,  4>(pcA, pcB, r4A, r4B, wpk + W_R, bpk + B_R);
#pragma unroll
    for (int j = 0; j < 4; ++j) {
        c4A[j] += fmaxf(r4A[j], 0.f);
        c4B[j] += fmaxf(r4B[j], 0.f);
    }
    h2 phA[2], phB[2];
    phA[0] = __builtin_amdgcn_cvt_pkrtz(c4A[0], c4A[1]);
    phA[1] = __builtin_amdgcn_cvt_pkrtz(c4A[2], c4A[3]);
    phB[0] = __builtin_amdgcn_cvt_pkrtz(c4B[0], c4B[1]);
    phB[1] = __builtin_amdgcn_cvt_pkrtz(c4B[2], c4B[3]);
    float ohA[1], ohB[1];
    layer_dot<4,  1>(phA, phB, ohA, ohB, wpk + W_H, bpk + B_H);
    out[r0] = fast_sigmoid(ohA[0]);
    out[r1] = fast_sigmoid(ohB[0]);
}

extern "C" void kernel_launch(void* const* d_in, const int* in_sizes, int n_in,
                              void* d_out, int out_size, void* d_ws, size_t ws_size,
                              hipStream_t stream) {
    const float* x    = (const float*)d_in[0];
    const float* bn_g = (const float*)d_in[1];
    const float* bn_b = (const float*)d_in[2];
    const float* w_fm = (const float*)d_in[3];
    const float* b_fm = (const float*)d_in[4];
    const float* w_c1 = (const float*)d_in[5];
    const float* b_c1 = (const float*)d_in[6];
    const float* w_p1 = (const float*)d_in[7];
    const float* b_p1 = (const float*)d_in[8];
    const float* w_c2 = (const float*)d_in[9];
    const float* b_c2 = (const float*)d_in[10];
    const float* w_p2 = (const float*)d_in[11];
    const float* b_p2 = (const float*)d_in[12];
    const float* w_c3 = (const float*)d_in[13];
    const float* b_c3 = (const float*)d_in[14];
    const float* w_r  = (const float*)d_in[15];
    const float* b_r  = (const float*)d_in[16];
    const float* w_h  = (const float*)d_in[17];
    const float* b_h  = (const float*)d_in[18];
    float* out = (float*)d_out;
    float* ws  = (float*)d_ws;

    bn_stats<<<STAT_BLOCKS, 256, 0, stream>>>(
        x, ws, w_fm, b_fm, w_c1, b_c1, w_p1, b_p1, w_c2, b_c2,
        w_p2, b_p2, w_c3, b_c3, w_r, b_r, w_h, b_h);
    qcnn_main<<<MAIN_BLOCKS, 256, 0, stream>>>(x, bn_g, bn_b, ws, out);
}

// Round 9
// 140.787 us; speedup vs baseline: 1.1030x; 1.0161x over previous
//
#include <hip/hip_runtime.h>
#include <stdint.h>

#define B_ROWS 1048576
#define STAT_BLOCKS 512
#define MAIN_BLOCKS 2048            // 256 thr x 2 rows

typedef __fp16 h2 __attribute__((ext_vector_type(2)));

// ws float layout:
//  [16 .. 16+8192)       per-block bn partials: 512 blocks x 16 floats
//  [8208 .. 8578)        packed f16x2 weights (uint32), 370 dwords  (raw, no BN fold)
//  [8578 .. 8643)        f32 biases, 65 floats
#define PART_OFF 16
#define WPK_OFF 8208
#define BIA_OFF 8578
#define W_FM 0
#define W_C1 64
#define W_P1 192
#define W_C2 288
#define W_P2 336
#define W_C3 352
#define W_R  360
#define W_H  368
#define B_FM 0
#define B_C1 16
#define B_P1 32
#define B_C2 44
#define B_P2 52
#define B_C3 56
#define B_R  60
#define B_H  64

__device__ __forceinline__ float exp_tanh(float x) {   // LUT fill only
    float e = __builtin_amdgcn_exp2f(x * 2.8853900817779268f);
    return 1.0f - 2.0f * __builtin_amdgcn_rcpf(e + 1.0f);
}

__device__ __forceinline__ float fast_sigmoid(float x) {
    float e = __builtin_amdgcn_exp2f(x * -1.4426950408889634f);
    return __builtin_amdgcn_rcpf(1.0f + e);
}

// ---- raw weight packing (no BN fold), used by bn_stats block 0 ----------------
template<int DIN, int DOUT>
__device__ void pack_layer(const float* __restrict__ w, const float* __restrict__ b,
                           uint32_t* __restrict__ wdst, float* __restrict__ bdst) {
    for (int idx = threadIdx.x; idx < DOUT * (DIN / 2); idx += blockDim.x) {
        int j = idx / (DIN / 2), i2 = idx % (DIN / 2);
        h2 h;
        h.x = (__fp16)w[(2 * i2) * DOUT + j];
        h.y = (__fp16)w[(2 * i2 + 1) * DOUT + j];
        wdst[j * (DIN / 2) + i2] = __builtin_bit_cast(uint32_t, h);
    }
    for (int j = threadIdx.x; j < DOUT; j += blockDim.x) bdst[j] = b[j];
}

// ---------------- pass 1: partials (512 blocks) + block0 packs weights ---------
__global__ __launch_bounds__(256) void bn_stats(
    const float* __restrict__ x, float* __restrict__ ws,
    const float* __restrict__ w_fm, const float* __restrict__ b_fm,
    const float* __restrict__ w_c1, const float* __restrict__ b_c1,
    const float* __restrict__ w_p1, const float* __restrict__ b_p1,
    const float* __restrict__ w_c2, const float* __restrict__ b_c2,
    const float* __restrict__ w_p2, const float* __restrict__ b_p2,
    const float* __restrict__ w_c3, const float* __restrict__ b_c3,
    const float* __restrict__ w_r,  const float* __restrict__ b_r,
    const float* __restrict__ w_h,  const float* __restrict__ b_h)
{
    const int tid = blockIdx.x * 256 + threadIdx.x;   // 0..131071
    float s[8], q[8];
#pragma unroll
    for (int c = 0; c < 8; ++c) { s[c] = 0.f; q[c] = 0.f; }
    const float4* x4 = (const float4*)x;
#pragma unroll
    for (int k = 0; k < 8; ++k) {
        int r = tid + k * 131072;
        float4 a = x4[2 * r];
        float4 b = x4[2 * r + 1];
        s[0] += a.x; s[1] += a.y; s[2] += a.z; s[3] += a.w;
        s[4] += b.x; s[5] += b.y; s[6] += b.z; s[7] += b.w;
        q[0] += a.x * a.x; q[1] += a.y * a.y; q[2] += a.z * a.z; q[3] += a.w * a.w;
        q[4] += b.x * b.x; q[5] += b.y * b.y; q[6] += b.z * b.z; q[7] += b.w * b.w;
    }
#pragma unroll
    for (int off = 32; off > 0; off >>= 1) {
#pragma unroll
        for (int c = 0; c < 8; ++c) {
            s[c] += __shfl_down(s[c], off);
            q[c] += __shfl_down(q[c], off);
        }
    }
    __shared__ float red[4][16];
    const int lane = threadIdx.x & 63;
    const int wave = threadIdx.x >> 6;
    if (lane == 0) {
#pragma unroll
        for (int c = 0; c < 8; ++c) { red[wave][c] = s[c]; red[wave][8 + c] = q[c]; }
    }
    __syncthreads();
    if (threadIdx.x < 16) {
        float acc = red[0][threadIdx.x] + red[1][threadIdx.x] +
                    red[2][threadIdx.x] + red[3][threadIdx.x];
        ws[PART_OFF + blockIdx.x * 16 + threadIdx.x] = acc;   // plain store
    }
    // block 0: pack all weights (independent of stats)
    if (blockIdx.x == 0) {
        uint32_t* wpk = (uint32_t*)(ws + WPK_OFF);
        float*    bpk = ws + BIA_OFF;
        pack_layer<8, 16>(w_fm, b_fm, wpk + W_FM, bpk + B_FM);
        pack_layer<16,16>(w_c1, b_c1, wpk + W_C1, bpk + B_C1);
        pack_layer<16,12>(w_p1, b_p1, wpk + W_P1, bpk + B_P1);
        pack_layer<12, 8>(w_c2, b_c2, wpk + W_C2, bpk + B_C2);
        pack_layer<8,  4>(w_p2, b_p2, wpk + W_P2, bpk + B_P2);
        pack_layer<4,  4>(w_c3, b_c3, wpk + W_C3, bpk + B_C3);
        pack_layer<4,  4>(w_r,  b_r,  wpk + W_R,  bpk + B_R);
        pack_layer<4,  1>(w_h,  b_h,  wpk + W_H,  bpk + B_H);
    }
}

// ------- nearest-entry tanh LUT: 8192 centers on [-4,4], h = 1/1024 ------------
__device__ __forceinline__ float lut_tanh(float x, const float* __restrict__ lut) {
    float t = fmaf(x, 1024.0f, 4096.0f);                   // [-4,4] -> [0,8192)
    t = __builtin_amdgcn_fmed3f(t, 0.0f, 8191.0f);         // clamp tails
    return lut[(int)t];                                    // trunc -> interval idx
}

// ---------------- dot2 dual-row layer ------------------------------------------
template<int DIN, int DOUT>
__device__ __forceinline__ void layer_dot(const h2* __restrict__ apkA, const h2* __restrict__ apkB,
                                          float* __restrict__ outA, float* __restrict__ outB,
                                          const uint32_t* __restrict__ wpk,
                                          const float* __restrict__ bias) {
#pragma unroll
    for (int j = 0; j < DOUT; ++j) {
        float accA = bias[j];
        float accB = accA;
#pragma unroll
        for (int i2 = 0; i2 < DIN / 2; ++i2) {
            h2 w = __builtin_bit_cast(h2, wpk[j * (DIN / 2) + i2]);
            accA = __builtin_amdgcn_fdot2(apkA[i2], w, accA, false);
            accB = __builtin_amdgcn_fdot2(apkB[i2], w, accB, false);
        }
        outA[j] = accA;
        outB[j] = accB;
    }
}

template<int N>
__device__ __forceinline__ void tanh_pack(const float* __restrict__ inA, const float* __restrict__ inB,
                                          h2* __restrict__ pkA, h2* __restrict__ pkB,
                                          const float* __restrict__ lut) {
#pragma unroll
    for (int k = 0; k < N / 2; ++k) {
        float a0 = lut_tanh(inA[2 * k], lut);
        float a1 = lut_tanh(inA[2 * k + 1], lut);
        float b0 = lut_tanh(inB[2 * k], lut);
        float b1 = lut_tanh(inB[2 * k + 1], lut);
        pkA[k] = __builtin_amdgcn_cvt_pkrtz(a0, a1);
        pkB[k] = __builtin_amdgcn_cvt_pkrtz(b0, b1);
    }
}

// ---------------- pass 2: inline stats-reduce + normalize + MLP chain ----------
__global__ __launch_bounds__(256) void qcnn_main(
    const float* __restrict__ x,
    const float* __restrict__ bn_g, const float* __restrict__ bn_b,
    const float* __restrict__ ws, float* __restrict__ out)
{
    // issue x loads first (overlap prologue)
    const int tid = blockIdx.x * 256 + threadIdx.x;
    const int r0 = tid, r1 = tid + (B_ROWS / 2);
    const float4* x4 = (const float4*)x;
    float4 xa0 = x4[2 * r0], xa1 = x4[2 * r0 + 1];
    float4 xb0 = x4[2 * r1], xb1 = x4[2 * r1 + 1];

    __shared__ float lut[8192];
    __shared__ float accs[16][17];
    __shared__ float scs[8], shs[8];

    // LUT fill: 32 entries/thread, centers; overlaps x-load latency
    {
        const float h = 0.0009765625f;        // 1/1024
#pragma unroll
        for (int k = 0; k < 32; ++k) {
            int i = threadIdx.x + k * 256;
            float xc = fmaf((float)i + 0.5f, h, -4.0f);
            lut[i] = exp_tanh(xc);
        }
    }
    // per-block redundant stats reduce: 512 x 16 partials (L2-hit)
    {
        const int f = threadIdx.x & 15;
        const int chunk = threadIdx.x >> 4;          // 0..15, each sums 32 blocks
        const float* p = ws + PART_OFF + (chunk * 32) * 16 + f;
        float a = 0.f;
#pragma unroll 8
        for (int b = 0; b < 32; ++b) a += p[b * 16];
        accs[chunk][f] = a;
    }
    __syncthreads();
    if (threadIdx.x < 16) {
        float t = 0.f;
#pragma unroll
        for (int c = 0; c < 16; ++c) t += accs[c][threadIdx.x];
        accs[0][threadIdx.x] = t;
    }
    __syncthreads();
    if (threadIdx.x < 8) {
        const float invB = 1.0f / (float)B_ROWS;
        int c = threadIdx.x;
        float mu  = accs[0][c] * invB;
        float var = fmaf(-mu, mu, accs[0][8 + c] * invB);
        float s   = bn_g[c] * rsqrtf(var + 1e-5f);
        scs[c] = s;
        shs[c] = fmaf(-mu, s, bn_b[c]);
    }
    __syncthreads();

    float sc[8], sh[8];
#pragma unroll
    for (int c = 0; c < 8; ++c) { sc[c] = scs[c]; sh[c] = shs[c]; }

    const uint32_t* wpk = (const uint32_t*)(ws + WPK_OFF);
    const float*    bpk = ws + BIA_OFF;

    // normalize in f32, then quantize to f16 pairs
    float nA[8], nB[8];
    nA[0] = fmaf(xa0.x, sc[0], sh[0]); nA[1] = fmaf(xa0.y, sc[1], sh[1]);
    nA[2] = fmaf(xa0.z, sc[2], sh[2]); nA[3] = fmaf(xa0.w, sc[3], sh[3]);
    nA[4] = fmaf(xa1.x, sc[4], sh[4]); nA[5] = fmaf(xa1.y, sc[5], sh[5]);
    nA[6] = fmaf(xa1.z, sc[6], sh[6]); nA[7] = fmaf(xa1.w, sc[7], sh[7]);
    nB[0] = fmaf(xb0.x, sc[0], sh[0]); nB[1] = fmaf(xb0.y, sc[1], sh[1]);
    nB[2] = fmaf(xb0.z, sc[2], sh[2]); nB[3] = fmaf(xb0.w, sc[3], sh[3]);
    nB[4] = fmaf(xb1.x, sc[4], sh[4]); nB[5] = fmaf(xb1.y, sc[5], sh[5]);
    nB[6] = fmaf(xb1.z, sc[6], sh[6]); nB[7] = fmaf(xb1.w, sc[7], sh[7]);
    h2 a8[4], b8[4];
#pragma unroll
    for (int k = 0; k < 4; ++k) {
        a8[k] = __builtin_amdgcn_cvt_pkrtz(nA[2 * k], nA[2 * k + 1]);
        b8[k] = __builtin_amdgcn_cvt_pkrtz(nB[2 * k], nB[2 * k + 1]);
    }

    float oA[16], oB[16]; h2 pA[8], pB[8];
    layer_dot<8, 16>(a8, b8, oA, oB, wpk + W_FM, bpk + B_FM);
    tanh_pack<16>(oA, oB, pA, pB, lut);
    float o2A[16], o2B[16]; h2 p2A[8], p2B[8];
    layer_dot<16,16>(pA, pB, o2A, o2B, wpk + W_C1, bpk + B_C1);
    tanh_pack<16>(o2A, o2B, p2A, p2B, lut);
    float o3A[12], o3B[12]; h2 p3A[6], p3B[6];
    layer_dot<16,12>(p2A, p2B, o3A, o3B, wpk + W_P1, bpk + B_P1);
    tanh_pack<12>(o3A, o3B, p3A, p3B, lut);
    float o4A[8], o4B[8]; h2 p4A[4], p4B[4];
    layer_dot<12, 8>(p3A, p3B, o4A, o4B, wpk + W_C2, bpk + B_C2);
    tanh_pack<8>(o4A, o4B, p4A, p4B, lut);
    float o5A[4], o5B[4]; h2 p5A[2], p5B[2];
    layer_dot<8,  4>(p4A, p4B, o5A, o5B, wpk + W_P2, bpk + B_P2);
    tanh_pack<4>(o5A, o5B, p5A, p5B, lut);
    float c4A[4], c4B[4];
    layer_dot<4,  4>(p5A, p5B, c4A, c4B, wpk + W_C3, bpk + B_C3);
#pragma unroll
    for (int j = 0; j < 4; ++j) {
        c4A[j] = lut_tanh(c4A[j], lut);
        c4B[j] = lut_tanh(c4B[j], lut);
    }
    h2 pcA[2], pcB[2];
    pcA[0] = __builtin_amdgcn_cvt_pkrtz(c4A[0], c4A[1]);
    pcA[1] = __builtin_amdgcn_cvt_pkrtz(c4A[2], c4A[3]);
    pcB[0] = __builtin_amdgcn_cvt_pkrtz(c4B[0], c4B[1]);
    pcB[1] = __builtin_amdgcn_cvt_pkrtz(c4B[2], c4B[3]);
    float r4A[4], r4B[4];
    layer_dot<4,  4>(pcA, pcB, r4A, r4B, wpk + W_R, bpk + B_R);
#pragma unroll
    for (int j = 0; j < 4; ++j) {
        c4A[j] += fmaxf(r4A[j], 0.f);
        c4B[j] += fmaxf(r4B[j], 0.f);
    }
    h2 phA[2], phB[2];
    phA[0] = __builtin_amdgcn_cvt_pkrtz(c4A[0], c4A[1]);
    phA[1] = __builtin_amdgcn_cvt_pkrtz(c4A[2], c4A[3]);
    phB[0] = __builtin_amdgcn_cvt_pkrtz(c4B[0], c4B[1]);
    phB[1] = __builtin_amdgcn_cvt_pkrtz(c4B[2], c4B[3]);
    float ohA[1], ohB[1];
    layer_dot<4,  1>(phA, phB, ohA, ohB, wpk + W_H, bpk + B_H);
    out[r0] = fast_sigmoid(ohA[0]);
    out[r1] = fast_sigmoid(ohB[0]);
}

extern "C" void kernel_launch(void* const* d_in, const int* in_sizes, int n_in,
                              void* d_out, int out_size, void* d_ws, size_t ws_size,
                              hipStream_t stream) {
    const float* x    = (const float*)d_in[0];
    const float* bn_g = (const float*)d_in[1];
    const float* bn_b = (const float*)d_in[2];
    const float* w_fm = (const float*)d_in[3];
    const float* b_fm = (const float*)d_in[4];
    const float* w_c1 = (const float*)d_in[5];
    const float* b_c1 = (const float*)d_in[6];
    const float* w_p1 = (const float*)d_in[7];
    const float* b_p1 = (const float*)d_in[8];
    const float* w_c2 = (const float*)d_in[9];
    const float* b_c2 = (const float*)d_in[10];
    const float* w_p2 = (const float*)d_in[11];
    const float* b_p2 = (const float*)d_in[12];
    const float* w_c3 = (const float*)d_in[13];
    const float* b_c3 = (const float*)d_in[14];
    const float* w_r  = (const float*)d_in[15];
    const float* b_r  = (const float*)d_in[16];
    const float* w_h  = (const float*)d_in[17];
    const float* b_h  = (const float*)d_in[18];
    float* out = (float*)d_out;
    float* ws  = (float*)d_ws;

    bn_stats<<<STAT_BLOCKS, 256, 0, stream>>>(
        x, ws, w_fm, b_fm, w_c1, b_c1, w_p1, b_p1, w_c2, b_c2,
        w_p2, b_p2, w_c3, b_c3, w_r, b_r, w_h, b_h);
    qcnn_main<<<MAIN_BLOCKS, 256, 0, stream>>>(x, bn_g, bn_b, ws, out);
}